// Round 20
// baseline (105.371 us; speedup 1.0000x reference)
//
#include <hip/hip_runtime.h>
#include <hip/hip_bf16.h>

// ClusterAggregator: B=8, N=32768, D=128, C=64, H=64
// out[b,c,:] = sum_{n: ca[b,n]==c} w_n * f[b,n,:], w = segment softmax of
// imp = sigmoid(relu(f@W1+b1)@W2+b2). Softmax shift-invariance: fixed shift 1.
//
// R20 = R18 (best, 45.3us: launch_bounds(512,2) + raw barriers + transpose-
// MFMA staging + swapped phase A) + IN-KERNEL TAIL REDUCE. Grid 512 == exact
// co-residency capacity (2 blocks/CU via 56.8KB LDS), so after the flush each
// block fences (device-scope L2 writeback), bumps a per-batch counter, spins
// until its batch's 64 slices arrived, then reduces its OWN (b,c)=blockIdx
// pair from IF-cache-hot partials. Removes the reduce dispatch + its gap.
// R19's depth-2 prefetch regressed (occupancy) -> reverted to depth 1.

#define B_ 8
#define N_ 32768
#define D_ 128
#define C_ 64
#define H_ 64

#define NTHREADS 512
#define NWAVES 8
#define ROWS_PER_BLOCK 512
#define NBLOCKS ((B_ * N_) / ROWS_PER_BLOCK)   // 512
#define SLICES (NBLOCKS / B_)                  // 64
#define NSS 4                                  // super-steps of 128 rows
#define RST 152   // ft ushort stride (304 B; 16B-aligned)
#define W1S 136   // w1l ushort stride

typedef float f32x4 __attribute__((ext_vector_type(4)));
typedef short s16x8 __attribute__((ext_vector_type(8)));

__device__ __forceinline__ short bf16rne(float x) {
    unsigned u = __float_as_uint(x);
    u = (u + 0x7FFFu + ((u >> 16) & 1u)) >> 16;
    return (short)u;
}
__device__ __forceinline__ float ubf_lo(unsigned u) {
    return __uint_as_float(u << 16);
}
__device__ __forceinline__ float ubf_hi(unsigned u) {
    return __uint_as_float(u & 0xFFFF0000u);
}

__device__ __forceinline__ s16x8 pk8(float4 a, float4 b) {
    union { s16x8 v; __hip_bfloat162 h[4]; } u;
    u.h[0] = __float22bfloat162_rn(make_float2(a.x, a.y));
    u.h[1] = __float22bfloat162_rn(make_float2(a.z, a.w));
    u.h[2] = __float22bfloat162_rn(make_float2(b.x, b.y));
    u.h[3] = __float22bfloat162_rn(make_float2(b.z, b.w));
    return u.v;
}

template <bool USE_WS>
__global__ __launch_bounds__(NTHREADS, 2)   // min 2 waves/EU: frees allocator
void ca_fused_kernel(const float* __restrict__ features,
                     const int* __restrict__ ca,
                     const float* __restrict__ b1,
                     const float* __restrict__ W2,
                     const float* __restrict__ b2,
                     const float* __restrict__ W1,   // fp32 [128][64]
                     float* __restrict__ out_sums,   // atomic path: [B*C*D]
                     float* __restrict__ denoms,     // atomic path: [B*C]
                     float* __restrict__ pout,       // ws path: [NBLOCKS][C*D]
                     float* __restrict__ pden,       // ws path: [NBLOCKS][C]
                     unsigned* __restrict__ cnt,     // ws path: [B_] arrival
                     float* __restrict__ out)        // ws path: final [B*C*D]
{
    __shared__ __align__(16) unsigned short ft[D_ * RST];   // 38.9 KB bf16 f^T
    __shared__ __align__(16) unsigned short w1l[H_ * W1S];  // 17.4 KB bf16 W1^T
    __shared__ __align__(16) unsigned int ceu[128];         // packed (e|c)/row
    __shared__ float red[NTHREADS];
    __shared__ float dns;

    const int tid  = threadIdx.x;
    const int lane = tid & 63;
    const int wave = tid >> 6;
    const int m    = lane & 15;
    const int kb   = lane >> 4;
    const int kbase = kb * 8;
    const int bidx = blockIdx.x;
    const int b    = bidx / SLICES;
    const int row_blk0 = bidx * ROWS_PER_BLOCK;

    // W1 (fp32, coalesced) -> bf16 W1^T in LDS: w1l[h][k] = bf16(W1[k][h])
    for (int i = tid; i < H_ * D_; i += NTHREADS) {
        const int k = i >> 6, h = i & 63;
        w1l[h * W1S + k] = (unsigned short)bf16rne(W1[i]);
    }

    // per-lane epilogue constants: this lane's 16 hcols = c4*16 + kb*4 + q
    f32x4 w2v[4];          // fp32 (precision-critical)
    unsigned b1p[8];       // bf16-packed pairs (b1 == 0 here: exact)
#pragma unroll
    for (int c4 = 0; c4 < 4; ++c4) {
#pragma unroll
        for (int qq = 0; qq < 4; ++qq)
            w2v[c4][qq] = W2[c4 * 16 + kb * 4 + qq];
#pragma unroll
        for (int hh = 0; hh < 2; ++hh) {
            const int i0 = c4 * 16 + kb * 4 + hh * 2;
            b1p[c4 * 2 + hh] =
                ((unsigned)(unsigned short)bf16rne(b1[i0 + 1]) << 16) |
                (unsigned)(unsigned short)bf16rne(b1[i0]);
        }
    }
    const float b2v = b2[0];

    const int CH = wave >> 1;   // this wave's cluster chunk (16 clusters)
    const int dh = wave & 1;    // this wave's d-half (64 dims)

    f32x4 accS[4];
    f32x4 accD = (f32x4){0.f, 0.f, 0.f, 0.f};
#pragma unroll
    for (int nt = 0; nt < 4; ++nt) accS[nt] = (f32x4){0.f, 0.f, 0.f, 0.f};

    // ones-column B fragment for denominator MFMA: B[k][n] = (n==0)
    s16x8 bones;
    {
        const short o = (m == 0) ? (short)0x3F80 : (short)0;
#pragma unroll
        for (int j = 0; j < 8; ++j) bones[j] = o;
    }
    // identity-column B frags for the transpose MFMA
    s16x8 bI0, bI1;
#pragma unroll
    for (int j = 0; j < 8; ++j) {
        bI0[j] = (kbase + j == m)      ? (short)0x3F80 : (short)0;
        bI1[j] = (kbase + j == 16 + m) ? (short)0x3F80 : (short)0;
    }

    // register prefetch (depth 1): lane owns row wave*16+m
    const float* fbase = features + (long long)(row_blk0 + wave * 16 + m) * D_;
    float4 pf[8];
#pragma unroll
    for (int ks = 0; ks < 4; ++ks) {
        pf[2 * ks]     = *(const float4*)(fbase + ks * 32 + kbase);
        pf[2 * ks + 1] = *(const float4*)(fbase + ks * 32 + kbase + 4);
    }
    int cv = 0;
    if (lane < 16) cv = ca[row_blk0 + wave * 16 + lane];

    __syncthreads();   // w1l ready

#pragma unroll
    for (int ss = 0; ss < NSS; ++ss) {
        s16x8 af[4];
#pragma unroll
        for (int ks = 0; ks < 4; ++ks) af[ks] = pk8(pf[2 * ks], pf[2 * ks + 1]);
        const int cvc = cv;

        if (ss + 1 < NSS) {
            const float* fn = fbase + (ss + 1) * 128 * D_;
#pragma unroll
            for (int ks = 0; ks < 4; ++ks) {
                pf[2 * ks]     = *(const float4*)(fn + ks * 32 + kbase);
                pf[2 * ks + 1] = *(const float4*)(fn + ks * 32 + kbase + 4);
            }
            if (lane < 16) cv = ca[row_blk0 + (ss + 1) * 128 + wave * 16 + lane];
        }
        __builtin_amdgcn_sched_barrier(0);

        // ---- ft staging via transpose-MFMA + b64 writes ----
        const int rg0 = wave * 16 + kb * 4;
#pragma unroll
        for (int ks = 0; ks < 4; ++ks) {
            const f32x4 z = (f32x4){0.f, 0.f, 0.f, 0.f};
            const f32x4 t0 = __builtin_amdgcn_mfma_f32_16x16x32_bf16(af[ks], bI0, z, 0, 0, 0);
            const f32x4 t1 = __builtin_amdgcn_mfma_f32_16x16x32_bf16(af[ks], bI1, z, 0, 0, 0);
            union { uint2 u; __hip_bfloat162 h[2]; } p0, p1;
            p0.h[0] = __float22bfloat162_rn(make_float2(t0[0], t0[1]));
            p0.h[1] = __float22bfloat162_rn(make_float2(t0[2], t0[3]));
            p1.h[0] = __float22bfloat162_rn(make_float2(t1[0], t1[1]));
            p1.h[1] = __float22bfloat162_rn(make_float2(t1[2], t1[3]));
            *(uint2*)&ft[(ks * 32 + m) * RST + rg0]      = p0.u;
            *(uint2*)&ft[(ks * 32 + 16 + m) * RST + rg0] = p1.u;
        }

        // ---- phase A (swapped): h^T = W1^T @ f^T ----
        float tp = 0.f;
#pragma unroll
        for (int c4 = 0; c4 < 4; ++c4) {
            f32x4 hc = (f32x4){0.f, 0.f, 0.f, 0.f};
#pragma unroll
            for (int ks = 0; ks < 4; ++ks) {
                const s16x8 w = *(const s16x8*)&w1l[(c4 * 16 + m) * W1S +
                                                    ks * 32 + kbase];
                hc = __builtin_amdgcn_mfma_f32_16x16x32_bf16(w, af[ks], hc, 0, 0, 0);
            }
            const float b0  = ubf_lo(b1p[c4 * 2]),     bb1 = ubf_hi(b1p[c4 * 2]);
            const float b2_ = ubf_lo(b1p[c4 * 2 + 1]), b3  = ubf_hi(b1p[c4 * 2 + 1]);
            tp = fmaf(fmaxf(hc[0] + b0,  0.f), w2v[c4][0], tp);
            tp = fmaf(fmaxf(hc[1] + bb1, 0.f), w2v[c4][1], tp);
            tp = fmaf(fmaxf(hc[2] + b2_, 0.f), w2v[c4][2], tp);
            tp = fmaf(fmaxf(hc[3] + b3,  0.f), w2v[c4][3], tp);
        }
        tp += __shfl_xor(tp, 16, 64);
        tp += __shfl_xor(tp, 32, 64);
        const float pre = tp + b2v;
        const float imp = 1.f / (1.f + __expf(-pre));
        const float e   = __expf(imp - 1.f);
        if (lane < 16)
            ceu[wave * 16 + lane] =
                ((unsigned)(unsigned short)bf16rne(e) << 16) | (unsigned)cvc;

        asm volatile("s_waitcnt lgkmcnt(0)" ::: "memory");
        __builtin_amdgcn_s_barrier();

        // ---- phase B: every wave aggregates its (CH, dh) slice, 4 k-groups --
#pragma unroll
        for (int kg = 0; kg < 4; ++kg) {
            const uint4* cq = (const uint4*)&ceu[kg * 32 + kbase];
            const uint4 ua = cq[0], ub = cq[1];
            const unsigned uu[8] = {ua.x, ua.y, ua.z, ua.w, ub.x, ub.y, ub.z, ub.w};

            s16x8 afr;
#pragma unroll
            for (int j = 0; j < 8; ++j)
                afr[j] = ((int)(uu[j] & 0xFFu) == CH * 16 + m)
                             ? (short)(uu[j] >> 16) : (short)0;

#pragma unroll
            for (int nt = 0; nt < 4; ++nt) {
                const int d0 = (dh * 4 + nt) * 16 + m;
                const s16x8 bfv = *(const s16x8*)&ft[d0 * RST + kg * 32 + kbase];
                accS[nt] = __builtin_amdgcn_mfma_f32_16x16x32_bf16(
                    afr, bfv, accS[nt], 0, 0, 0);
            }
            if (dh == 0)
                accD = __builtin_amdgcn_mfma_f32_16x16x32_bf16(afr, bones, accD, 0, 0, 0);
        }

        __builtin_amdgcn_s_barrier();
    }

    // ---- flush: per-wave slices disjoint -> plain stores ----
#pragma unroll
    for (int nt = 0; nt < 4; ++nt)
#pragma unroll
        for (int qq = 0; qq < 4; ++qq) {
            const int idx = (CH * 16 + kb * 4 + qq) * D_ + (dh * 4 + nt) * 16 + m;
            if (USE_WS) pout[(size_t)bidx * (C_ * D_) + idx] = accS[nt][qq];
            else atomicAdd(&out_sums[b * (C_ * D_) + idx], accS[nt][qq]);
        }
    if (dh == 0 && m == 0) {
#pragma unroll
        for (int qq = 0; qq < 4; ++qq) {
            const int c = CH * 16 + kb * 4 + qq;
            if (USE_WS) pden[bidx * C_ + c] = accD[qq];
            else atomicAdd(&denoms[b * C_ + c], accD[qq]);
        }
    }

    if (!USE_WS) return;

    // ---- in-kernel tail reduce: this block reduces (b,c) = bidx ----
    __syncthreads();   // all stores issued & drained (vmcnt(0) semantics)
    if (tid == 0) {
        __threadfence();                     // device-scope visibility (G16)
        atomicAdd(&cnt[b], 1u);
        while (__hip_atomic_load(&cnt[b], __ATOMIC_ACQUIRE,
                                 __HIP_MEMORY_SCOPE_AGENT) < (unsigned)SLICES)
            __builtin_amdgcn_s_sleep(2);
    }
    __syncthreads();   // whole block waits on tid0's spin

    {
        const int c  = bidx & (C_ - 1);
        const int bb = b;
        const int d  = tid & 127;
        const int sg = tid >> 7;             // 0..3

        const float* pb = pout + ((size_t)(bb * SLICES + sg * 16)) * (C_ * D_)
                               + c * D_ + d;
        float s = 0.f;
#pragma unroll 4
        for (int i = 0; i < 16; ++i) s += pb[(size_t)i * (C_ * D_)];
        red[tid] = s;

        float dnv = 0.f;
        if (tid < SLICES) dnv = pden[(bb * SLICES + tid) * C_ + c];
        if (tid < 64) {
#pragma unroll
            for (int off = 32; off > 0; off >>= 1)
                dnv += __shfl_xor(dnv, off, 64);
            if (tid == 0) dns = dnv;
        }
        __syncthreads();

        if (tid < 128) {
            const float tot = red[tid] + red[tid + 128] +
                              red[tid + 256] + red[tid + 384];
            const float dn = dns;
            out[(size_t)bidx * D_ + tid] = (dn > 0.f) ? (tot / dn) : 0.f;
        }
    }
}

__global__ void ca_zero_kernel(float* __restrict__ out_sums,
                               float* __restrict__ denoms)
{
    const int i = blockIdx.x * blockDim.x + threadIdx.x;
    if (i < B_ * C_ * D_) out_sums[i] = 0.f;
    if (i < B_ * C_)      denoms[i] = 0.f;
}

__global__ void ca_finalize_kernel(float* __restrict__ out_sums,
                                   const float* __restrict__ denoms)
{
    const int i = blockIdx.x * blockDim.x + threadIdx.x;
    if (i >= B_ * C_ * D_) return;
    const int bc = i >> 7;
    const float den = denoms[bc];
    const float v = out_sums[i];
    out_sums[i] = (den > 0.f) ? (v / den) : 0.f;
}

extern "C" void kernel_launch(void* const* d_in, const int* in_sizes, int n_in,
                              void* d_out, int out_size, void* d_ws, size_t ws_size,
                              hipStream_t stream) {
    const float* features = (const float*)d_in[0];
    const int*   ca       = (const int*)  d_in[1];
    const float* W1       = (const float*)d_in[2];
    const float* b1       = (const float*)d_in[3];
    const float* W2       = (const float*)d_in[4];
    const float* b2       = (const float*)d_in[5];

    float* out = (float*)d_out;   // [B*C*D]

    // ws layout: [pden 128KB][pout 16MB][cnt 32B]
    float* pden = (float*)d_ws;
    float* pout = (float*)((char*)d_ws + 131072);
    unsigned* cnt = (unsigned*)((char*)d_ws + 131072 +
                                (size_t)NBLOCKS * C_ * D_ * 4);
    const size_t need_full = 131072 + (size_t)NBLOCKS * C_ * D_ * 4 + B_ * 4;

    if (ws_size >= need_full) {
        hipMemsetAsync(cnt, 0, B_ * sizeof(unsigned), stream);
        ca_fused_kernel<true><<<NBLOCKS, NTHREADS, 0, stream>>>(
            features, ca, b1, W2, b2, W1, nullptr, nullptr, pout, pden, cnt, out);
    } else {
        // fallback: global-atomic flush (needs only pden prefix, 2 KB)
        ca_zero_kernel<<<(B_ * C_ * D_ + 255) / 256, 256, 0, stream>>>(out, pden);
        ca_fused_kernel<false><<<NBLOCKS, NTHREADS, 0, stream>>>(
            features, ca, b1, W2, b2, W1, out, pden, nullptr, nullptr, nullptr,
            nullptr);
        ca_finalize_kernel<<<(B_ * C_ * D_ + 255) / 256, 256, 0, stream>>>(out, pden);
    }
}

// Round 21
// 44.771 us; speedup vs baseline: 2.3536x; 2.3536x over previous
//
#include <hip/hip_runtime.h>
#include <hip/hip_bf16.h>

// ClusterAggregator: B=8, N=32768, D=128, C=64, H=64
// out[b,c,:] = sum_{n: ca[b,n]==c} w_n * f[b,n,:], w = segment softmax of
// imp = sigmoid(relu(f@W1+b1)@W2+b2). Softmax shift-invariance: fixed shift 1.
//
// R21 = exact revert to R18 (session best, 45.3us). R19 (depth-2 prefetch)
// and R20 (in-kernel spin reduce) both regressed -- R20 catastrophically
// (105us: cross-block spin exposed grid skew at 2 blocks/CU). R18 structure:
//  - launch_bounds(512,2): frees register allocator (VGPR=64 spill era fix)
//  - raw s_barrier + lgkmcnt(0)-only (counted vmcnt, never drained in-loop)
//  - ft staging via transpose-MFMA -> 8 ds_write_b64 (not 32 ds_write_b16)
//  - swapped phase A h^T = W1^T @ f^T: lane-local W2-reduce, 1 exp chain
//  - one-hot MFMA aggregation, per-wave disjoint slices, ws partials+reduce

#define B_ 8
#define N_ 32768
#define D_ 128
#define C_ 64
#define H_ 64

#define NTHREADS 512
#define NWAVES 8
#define ROWS_PER_BLOCK 512
#define NBLOCKS ((B_ * N_) / ROWS_PER_BLOCK)   // 512
#define SLICES (NBLOCKS / B_)                  // 64
#define NSS 4                                  // super-steps of 128 rows
#define RST 152   // ft ushort stride (304 B; 16B-aligned)
#define W1S 136   // w1l ushort stride

typedef float f32x4 __attribute__((ext_vector_type(4)));
typedef short s16x8 __attribute__((ext_vector_type(8)));

__device__ __forceinline__ short bf16rne(float x) {
    unsigned u = __float_as_uint(x);
    u = (u + 0x7FFFu + ((u >> 16) & 1u)) >> 16;
    return (short)u;
}
__device__ __forceinline__ float ubf_lo(unsigned u) {
    return __uint_as_float(u << 16);
}
__device__ __forceinline__ float ubf_hi(unsigned u) {
    return __uint_as_float(u & 0xFFFF0000u);
}

__device__ __forceinline__ s16x8 pk8(float4 a, float4 b) {
    union { s16x8 v; __hip_bfloat162 h[4]; } u;
    u.h[0] = __float22bfloat162_rn(make_float2(a.x, a.y));
    u.h[1] = __float22bfloat162_rn(make_float2(a.z, a.w));
    u.h[2] = __float22bfloat162_rn(make_float2(b.x, b.y));
    u.h[3] = __float22bfloat162_rn(make_float2(b.z, b.w));
    return u.v;
}

template <bool USE_WS>
__global__ __launch_bounds__(NTHREADS, 2)   // min 2 waves/EU: frees allocator
void ca_fused_kernel(const float* __restrict__ features,
                     const int* __restrict__ ca,
                     const float* __restrict__ b1,
                     const float* __restrict__ W2,
                     const float* __restrict__ b2,
                     const float* __restrict__ W1,   // fp32 [128][64]
                     float* __restrict__ out_sums,   // atomic path: [B*C*D]
                     float* __restrict__ denoms,     // atomic path: [B*C]
                     float* __restrict__ pout,       // ws path: [NBLOCKS][C*D]
                     float* __restrict__ pden)       // ws path: [NBLOCKS][C]
{
    __shared__ __align__(16) unsigned short ft[D_ * RST];   // 38.9 KB bf16 f^T
    __shared__ __align__(16) unsigned short w1l[H_ * W1S];  // 17.4 KB bf16 W1^T
    __shared__ __align__(16) unsigned int ceu[128];         // packed (e|c)/row

    const int tid  = threadIdx.x;
    const int lane = tid & 63;
    const int wave = tid >> 6;
    const int m    = lane & 15;
    const int kb   = lane >> 4;
    const int kbase = kb * 8;
    const int bidx = blockIdx.x;
    const int b    = bidx / SLICES;
    const int row_blk0 = bidx * ROWS_PER_BLOCK;

    // W1 (fp32, coalesced) -> bf16 W1^T in LDS: w1l[h][k] = bf16(W1[k][h])
    for (int i = tid; i < H_ * D_; i += NTHREADS) {
        const int k = i >> 6, h = i & 63;
        w1l[h * W1S + k] = (unsigned short)bf16rne(W1[i]);
    }

    // per-lane epilogue constants: this lane's 16 hcols = c4*16 + kb*4 + q
    f32x4 w2v[4];          // fp32 (precision-critical)
    unsigned b1p[8];       // bf16-packed pairs (b1 == 0 here: exact)
#pragma unroll
    for (int c4 = 0; c4 < 4; ++c4) {
#pragma unroll
        for (int qq = 0; qq < 4; ++qq)
            w2v[c4][qq] = W2[c4 * 16 + kb * 4 + qq];
#pragma unroll
        for (int hh = 0; hh < 2; ++hh) {
            const int i0 = c4 * 16 + kb * 4 + hh * 2;
            b1p[c4 * 2 + hh] =
                ((unsigned)(unsigned short)bf16rne(b1[i0 + 1]) << 16) |
                (unsigned)(unsigned short)bf16rne(b1[i0]);
        }
    }
    const float b2v = b2[0];

    const int CH = wave >> 1;   // this wave's cluster chunk (16 clusters)
    const int dh = wave & 1;    // this wave's d-half (64 dims)

    f32x4 accS[4];
    f32x4 accD = (f32x4){0.f, 0.f, 0.f, 0.f};
#pragma unroll
    for (int nt = 0; nt < 4; ++nt) accS[nt] = (f32x4){0.f, 0.f, 0.f, 0.f};

    // ones-column B fragment for denominator MFMA: B[k][n] = (n==0)
    s16x8 bones;
    {
        const short o = (m == 0) ? (short)0x3F80 : (short)0;
#pragma unroll
        for (int j = 0; j < 8; ++j) bones[j] = o;
    }
    // identity-column B frags for the transpose MFMA:
    // bI0[k][n] = (k == n), bI1[k][n] = (k == 16+n)  (k = kb*8+j, n = m)
    s16x8 bI0, bI1;
#pragma unroll
    for (int j = 0; j < 8; ++j) {
        bI0[j] = (kbase + j == m)      ? (short)0x3F80 : (short)0;
        bI1[j] = (kbase + j == 16 + m) ? (short)0x3F80 : (short)0;
    }

    // register prefetch: lane owns row wave*16+m
    const float* fbase = features + (long long)(row_blk0 + wave * 16 + m) * D_;
    float4 pf[8];
#pragma unroll
    for (int ks = 0; ks < 4; ++ks) {
        pf[2 * ks]     = *(const float4*)(fbase + ks * 32 + kbase);
        pf[2 * ks + 1] = *(const float4*)(fbase + ks * 32 + kbase + 4);
    }
    int cv = 0;
    if (lane < 16) cv = ca[row_blk0 + wave * 16 + lane];

    __syncthreads();   // w1l ready (once; full drain harmless here)

#pragma unroll
    for (int ss = 0; ss < NSS; ++ss) {
        // consume prefetch -> bf16 A/B frags
        s16x8 af[4];
#pragma unroll
        for (int ks = 0; ks < 4; ++ks) af[ks] = pk8(pf[2 * ks], pf[2 * ks + 1]);
        const int cvc = cv;

        // issue prefetch for next super-step; pin issue point
        if (ss + 1 < NSS) {
            const float* fn = fbase + (ss + 1) * 128 * D_;
#pragma unroll
            for (int ks = 0; ks < 4; ++ks) {
                pf[2 * ks]     = *(const float4*)(fn + ks * 32 + kbase);
                pf[2 * ks + 1] = *(const float4*)(fn + ks * 32 + kbase + 4);
            }
            if (lane < 16) cv = ca[row_blk0 + (ss + 1) * 128 + wave * 16 + lane];
        }
        __builtin_amdgcn_sched_barrier(0);

        // ---- ft staging via transpose-MFMA + b64 writes ----
        // C = af x bI(sel): lane(m,kb) reg q = f[r=kb*4+q][ks*32+sel*16+m]
        // -> pack 4 r-consecutive bf16 -> ds_write_b64 at ft[d][wave*16+kb*4]
        const int rg0 = wave * 16 + kb * 4;
#pragma unroll
        for (int ks = 0; ks < 4; ++ks) {
            const f32x4 z = (f32x4){0.f, 0.f, 0.f, 0.f};
            const f32x4 t0 = __builtin_amdgcn_mfma_f32_16x16x32_bf16(af[ks], bI0, z, 0, 0, 0);
            const f32x4 t1 = __builtin_amdgcn_mfma_f32_16x16x32_bf16(af[ks], bI1, z, 0, 0, 0);
            union { uint2 u; __hip_bfloat162 h[2]; } p0, p1;
            p0.h[0] = __float22bfloat162_rn(make_float2(t0[0], t0[1]));
            p0.h[1] = __float22bfloat162_rn(make_float2(t0[2], t0[3]));
            p1.h[0] = __float22bfloat162_rn(make_float2(t1[0], t1[1]));
            p1.h[1] = __float22bfloat162_rn(make_float2(t1[2], t1[3]));
            *(uint2*)&ft[(ks * 32 + m) * RST + rg0]      = p0.u;
            *(uint2*)&ft[(ks * 32 + 16 + m) * RST + rg0] = p1.u;
        }

        // ---- phase A (swapped): h^T = W1^T @ f^T ----
        // A = w1l frag (lane m = hcol within chunk), B = af (lane m = row r).
        // C: lane(m,kb) reg q = h[r=m][hcol = c4*16 + kb*4 + q]
        float tp = 0.f;
#pragma unroll
        for (int c4 = 0; c4 < 4; ++c4) {
            f32x4 hc = (f32x4){0.f, 0.f, 0.f, 0.f};
#pragma unroll
            for (int ks = 0; ks < 4; ++ks) {
                const s16x8 w = *(const s16x8*)&w1l[(c4 * 16 + m) * W1S +
                                                    ks * 32 + kbase];
                hc = __builtin_amdgcn_mfma_f32_16x16x32_bf16(w, af[ks], hc, 0, 0, 0);
            }
            const float b0  = ubf_lo(b1p[c4 * 2]),     bb1 = ubf_hi(b1p[c4 * 2]);
            const float b2_ = ubf_lo(b1p[c4 * 2 + 1]), b3  = ubf_hi(b1p[c4 * 2 + 1]);
            tp = fmaf(fmaxf(hc[0] + b0,  0.f), w2v[c4][0], tp);
            tp = fmaf(fmaxf(hc[1] + bb1, 0.f), w2v[c4][1], tp);
            tp = fmaf(fmaxf(hc[2] + b2_, 0.f), w2v[c4][2], tp);
            tp = fmaf(fmaxf(hc[3] + b3,  0.f), w2v[c4][3], tp);
        }
        // reduce across kb groups: t for row r = m lands on every lane
        tp += __shfl_xor(tp, 16, 64);
        tp += __shfl_xor(tp, 32, 64);
        const float pre = tp + b2v;
        const float imp = 1.f / (1.f + __expf(-pre));
        const float e   = __expf(imp - 1.f);
        if (lane < 16)
            ceu[wave * 16 + lane] =
                ((unsigned)(unsigned short)bf16rne(e) << 16) | (unsigned)cvc;

        // barrier A: LDS writes (ft, ceu) visible -> lgkmcnt(0) only.
        asm volatile("s_waitcnt lgkmcnt(0)" ::: "memory");
        __builtin_amdgcn_s_barrier();

        // ---- phase B: every wave aggregates its (CH, dh) slice, 4 k-groups --
#pragma unroll
        for (int kg = 0; kg < 4; ++kg) {
            const uint4* cq = (const uint4*)&ceu[kg * 32 + kbase];
            const uint4 ua = cq[0], ub = cq[1];
            const unsigned uu[8] = {ua.x, ua.y, ua.z, ua.w, ub.x, ub.y, ub.z, ub.w};

            s16x8 afr;
#pragma unroll
            for (int j = 0; j < 8; ++j)
                afr[j] = ((int)(uu[j] & 0xFFu) == CH * 16 + m)
                             ? (short)(uu[j] >> 16) : (short)0;

#pragma unroll
            for (int nt = 0; nt < 4; ++nt) {
                const int d0 = (dh * 4 + nt) * 16 + m;
                const s16x8 bfv = *(const s16x8*)&ft[d0 * RST + kg * 32 + kbase];
                accS[nt] = __builtin_amdgcn_mfma_f32_16x16x32_bf16(
                    afr, bfv, accS[nt], 0, 0, 0);
            }
            if (dh == 0)
                accD = __builtin_amdgcn_mfma_f32_16x16x32_bf16(afr, bones, accD, 0, 0, 0);
        }

        // barrier B: phase-B LDS reads consumed into registers
        __builtin_amdgcn_s_barrier();
    }

    // ---- flush: per-wave slices disjoint -> plain stores (ws path) ----
#pragma unroll
    for (int nt = 0; nt < 4; ++nt)
#pragma unroll
        for (int qq = 0; qq < 4; ++qq) {
            const int idx = (CH * 16 + kb * 4 + qq) * D_ + (dh * 4 + nt) * 16 + m;
            if (USE_WS) pout[(size_t)bidx * (C_ * D_) + idx] = accS[nt][qq];
            else atomicAdd(&out_sums[b * (C_ * D_) + idx], accS[nt][qq]);
        }
    if (dh == 0 && m == 0) {
#pragma unroll
        for (int qq = 0; qq < 4; ++qq) {
            const int c = CH * 16 + kb * 4 + qq;
            if (USE_WS) pden[bidx * C_ + c] = accD[qq];
            else atomicAdd(&denoms[b * C_ + c], accD[qq]);
        }
    }
}

// Reduce SLICES partials per (b,c), divide by reduced denom, write out.
__global__ __launch_bounds__(512)
void ca_reduce_kernel(const float* __restrict__ pout,
                      const float* __restrict__ pden,
                      float* __restrict__ out)
{
    __shared__ float red[512];
    __shared__ float dns;

    const int bc = blockIdx.x;           // 0 .. B_*C_-1
    const int b  = bc >> 6;
    const int c  = bc & (C_ - 1);
    const int t  = threadIdx.x;
    const int d  = t & 127;
    const int sg = t >> 7;               // 0..3

    const float* pb = pout + ((size_t)(b * SLICES + sg * 16)) * (C_ * D_)
                           + c * D_ + d;
    float s = 0.f;
#pragma unroll 4
    for (int i = 0; i < 16; ++i) s += pb[(size_t)i * (C_ * D_)];
    red[t] = s;

    float dnv = 0.f;
    if (t < SLICES) dnv = pden[(b * SLICES + t) * C_ + c];
    if (t < 64) {
#pragma unroll
        for (int off = 32; off > 0; off >>= 1) dnv += __shfl_xor(dnv, off, 64);
        if (t == 0) dns = dnv;
    }
    __syncthreads();

    if (t < 128) {
        const float tot = red[t] + red[t + 128] + red[t + 256] + red[t + 384];
        const float dn = dns;
        out[(size_t)bc * D_ + t] = (dn > 0.f) ? (tot / dn) : 0.f;
    }
}

__global__ void ca_zero_kernel(float* __restrict__ out_sums,
                               float* __restrict__ denoms)
{
    const int i = blockIdx.x * blockDim.x + threadIdx.x;
    if (i < B_ * C_ * D_) out_sums[i] = 0.f;
    if (i < B_ * C_)      denoms[i] = 0.f;
}

__global__ void ca_finalize_kernel(float* __restrict__ out_sums,
                                   const float* __restrict__ denoms)
{
    const int i = blockIdx.x * blockDim.x + threadIdx.x;
    if (i >= B_ * C_ * D_) return;
    const int bc = i >> 7;
    const float den = denoms[bc];
    const float v = out_sums[i];
    out_sums[i] = (den > 0.f) ? (v / den) : 0.f;
}

extern "C" void kernel_launch(void* const* d_in, const int* in_sizes, int n_in,
                              void* d_out, int out_size, void* d_ws, size_t ws_size,
                              hipStream_t stream) {
    const float* features = (const float*)d_in[0];
    const int*   ca       = (const int*)  d_in[1];
    const float* W1       = (const float*)d_in[2];
    const float* b1       = (const float*)d_in[3];
    const float* W2       = (const float*)d_in[4];
    const float* b2       = (const float*)d_in[5];

    float* out = (float*)d_out;   // [B*C*D]

    // ws layout: [pden 128KB][pout 16MB]
    float* pden = (float*)d_ws;
    float* pout = (float*)((char*)d_ws + 131072);
    const size_t need_full = 131072 + (size_t)NBLOCKS * C_ * D_ * 4;

    if (ws_size >= need_full) {
        ca_fused_kernel<true><<<NBLOCKS, NTHREADS, 0, stream>>>(
            features, ca, b1, W2, b2, W1, nullptr, nullptr, pout, pden);
        ca_reduce_kernel<<<B_ * C_, 512, 0, stream>>>(pout, pden, out);
    } else {
        // fallback: global-atomic flush (needs only pden prefix, 2 KB)
        ca_zero_kernel<<<(B_ * C_ * D_ + 255) / 256, 256, 0, stream>>>(out, pden);
        ca_fused_kernel<false><<<NBLOCKS, NTHREADS, 0, stream>>>(
            features, ca, b1, W2, b2, W1, out, pden, nullptr, nullptr);
        ca_finalize_kernel<<<(B_ * C_ * D_ + 255) / 256, 256, 0, stream>>>(out, pden);
    }
}